// Round 11
// baseline (1189.634 us; speedup 1.0000x reference)
//
#include <hip/hip_runtime.h>
#include <hip/hip_cooperative_groups.h>
#include <math.h>

namespace cg = cooperative_groups;

#define B_SZ 2
#define SEQ  1024
#define DM   1024
#define DI   2048
#define NST  16
#define RNK  64
#define XPD  96            // RNK + 2*NST
#define M_TOT (B_SZ*SEQ)   // 2048
#define NC   32            // scan chunks
#define LC   (SEQ/NC)      // 32 steps per chunk
#define NCH  65536         // total chains = B_SZ*DI*NST
#define CGB  512           // cooperative grid blocks (2/CU: VGPR<=256 suffices)

typedef unsigned short ushort_t;
typedef __attribute__((ext_vector_type(8))) short short8;   // 8 bf16 = 4 VGPRs
typedef __attribute__((ext_vector_type(4))) float f32x4;

#if __has_builtin(__builtin_amdgcn_exp2f)
#define EXP2F __builtin_amdgcn_exp2f
#else
#define EXP2F exp2f
#endif
#define LOG2E 1.44269504f

__device__ __forceinline__ ushort_t f2bf(float f) {
    unsigned u = __float_as_uint(f);
    u += 0x7fff + ((u >> 16) & 1);           // round-to-nearest-even
    return (ushort_t)(u >> 16);
}
__device__ __forceinline__ float bf2f(ushort_t v) {
    return __uint_as_float(((unsigned)v) << 16);
}

// ---------------------------------------------------------------------------
// One-shot prologue conversion (segmented by blockIdx): 14720 blocks.
// ---------------------------------------------------------------------------
__global__ __launch_bounds__(256)
void convert_all(const float* __restrict__ x,
                 const float* __restrict__ inWf, const float* __restrict__ inWb,
                 const float* __restrict__ outWf, const float* __restrict__ outWb,
                 const float* __restrict__ xpWf, const float* __restrict__ xpWb,
                 ushort_t* __restrict__ xbf, ushort_t* __restrict__ inWcat,
                 ushort_t* __restrict__ outWcat, ushort_t* __restrict__ xpWcat)
{
    int bid = blockIdx.x;
    const float* src; ushort_t* dst; int rel; int strided = 0;
    if (bid < 2048)       { rel = bid;         src = x;     dst = xbf; }
    else if (bid < 6144)  { rel = bid - 2048;  src = inWf;  dst = inWcat; }
    else if (bid < 10240) { rel = bid - 6144;  src = inWb;  dst = inWcat + (size_t)2 * DI * DM; }
    else if (bid < 12288) { rel = bid - 10240; src = outWf; dst = outWcat;      strided = 1; }
    else if (bid < 14336) { rel = bid - 12288; src = outWb; dst = outWcat + DI; strided = 1; }
    else if (bid < 14528) { rel = bid - 14336; src = xpWf;  dst = xpWcat; }
    else                  { rel = bid - 14528; src = xpWb;  dst = xpWcat + (size_t)XPD * DI; }
    int i = rel * 256 + threadIdx.x;
    float4 v = ((const float4*)src)[i];
    ushort4 o;
    o.x = f2bf(v.x); o.y = f2bf(v.y); o.z = f2bf(v.z); o.w = f2bf(v.w);
    if (!strided) {
        ((ushort4*)dst)[i] = o;
    } else {
        int row = i >> 9;                 // rowLen4 = DI/4 = 512
        int c4  = (i - (row << 9)) << 2;
        *(ushort4*)(dst + (size_t)row * (2 * DI) + c4) = o;
    }
}

// ---------------------------------------------------------------------------
// m97-style bf16 MFMA NT GEMM, 128x128 tile, BK=64, global_load_lds staging,
// XOR-swizzled unpadded LDS. OUT_BF16: D bf16 [M x ldD]; else fp32 partials.
// ---------------------------------------------------------------------------
__device__ __forceinline__ void load_lds16(const ushort_t* g, ushort_t* l) {
    __builtin_amdgcn_global_load_lds(
        (const __attribute__((address_space(1))) void*)g,
        (__attribute__((address_space(3))) void*)l, 16, 0, 0);
}

template<bool OUT_BF16>
__global__ __launch_bounds__(256)
void gemm_gll(const ushort_t* __restrict__ A, const ushort_t* __restrict__ W,
              void* __restrict__ D, int M, int N, int K, int kLen, int ldD)
{
    __shared__ __align__(16) ushort_t As[128 * 64];
    __shared__ __align__(16) ushort_t Ws[128 * 64];
    const int t    = threadIdx.x;
    const int lane = t & 63;
    const int wave = t >> 6;
    const int wr   = (wave >> 1) * 64;
    const int wc   = (wave & 1) * 64;

    const int m0 = blockIdx.y * 128;
    const int n0 = blockIdx.x * 128;
    const int kStart = blockIdx.z * kLen;

    const int srow   = lane >> 3;
    const int gchunk = (lane & 7) ^ srow;

    f32x4 acc[4][4] = {};

    for (int k0 = kStart; k0 < kStart + kLen; k0 += 64) {
#pragma unroll
        for (int it = 0; it < 4; it++) {
            const int rb = wave * 32 + it * 8;
            load_lds16(A + (size_t)(m0 + rb + srow) * K + k0 + gchunk * 8, As + rb * 64);
            load_lds16(W + (size_t)(n0 + rb + srow) * K + k0 + gchunk * 8, Ws + rb * 64);
        }
        __syncthreads();
#pragma unroll
        for (int kk = 0; kk < 2; kk++) {
            const int kc = kk * 4 + (lane >> 4);
            short8 af[4], bf[4];
#pragma unroll
            for (int i = 0; i < 4; i++) {
                int r = wr + i * 16 + (lane & 15);
                af[i] = *(const short8*)(As + r * 64 + ((kc ^ (r & 7)) << 3));
            }
#pragma unroll
            for (int j = 0; j < 4; j++) {
                int r = wc + j * 16 + (lane & 15);
                bf[j] = *(const short8*)(Ws + r * 64 + ((kc ^ (r & 7)) << 3));
            }
#pragma unroll
            for (int i = 0; i < 4; i++)
#pragma unroll
                for (int j = 0; j < 4; j++)
                    acc[i][j] = __builtin_amdgcn_mfma_f32_16x16x32_bf16(
                        af[i], bf[j], acc[i][j], 0, 0, 0);
        }
        __syncthreads();
    }

    if (OUT_BF16) {
        ushort_t* Dp = (ushort_t*)D;
#pragma unroll
        for (int i = 0; i < 4; i++)
#pragma unroll
            for (int r = 0; r < 4; r++) {
                int m = m0 + wr + i * 16 + ((lane >> 4) << 2) + r;
#pragma unroll
                for (int j = 0; j < 4; j++) {
                    int n = n0 + wc + j * 16 + (lane & 15);
                    Dp[(size_t)m * ldD + n] = f2bf(acc[i][j][r]);
                }
            }
    } else {
        float* Dp = (float*)D + (size_t)blockIdx.z * M * ldD;
#pragma unroll
        for (int i = 0; i < 4; i++)
#pragma unroll
            for (int r = 0; r < 4; r++) {
                int m = m0 + wr + i * 16 + ((lane >> 4) << 2) + r;
#pragma unroll
                for (int j = 0; j < 4; j++) {
                    int n = n0 + wc + j * 16 + (lane & 15);
                    Dp[(size_t)m * ldD + n] = acc[i][j][r];
                }
            }
    }
}

// out = 0.5 * (P0 + P1 + P2 + P3)   [fallback]
__global__ __launch_bounds__(256)
void reduce4(const float* __restrict__ P, float* __restrict__ out)
{
    int i = blockIdx.x * 256 + threadIdx.x;
    const size_t S = (size_t)M_TOT * DM / 4;
    float4 a = ((const float4*)P)[i];
    float4 b = ((const float4*)P)[i + S];
    float4 c = ((const float4*)P)[i + 2 * S];
    float4 d = ((const float4*)P)[i + 3 * S];
    float4 o;
    o.x = 0.5f * (a.x + b.x + c.x + d.x);
    o.y = 0.5f * (a.y + b.y + c.y + d.y);
    o.z = 0.5f * (a.z + b.z + c.z + d.z);
    o.w = 0.5f * (a.w + b.w + c.w + d.w);
    ((float4*)out)[i] = o;
}

// ===========================================================================
// Shared device bodies for the middle phases (used by coop + fallback).
// ===========================================================================
#define LDSP 72

__device__ __forceinline__ void conv_body(int job, int tid,
    const ushort_t* xzall, const float* convWf, const float* convWb,
    const float* convBf, const float* convBb, ushort_t* ubf)
{
    int dir = job >> 12;
    int idx = (job & 4095) * 256 + tid;
    const float* convW = dir ? convWb : convWf;
    const float* convB = dir ? convBb : convBf;
    int di = (idx & (DI / 4 - 1)) << 2;
    int m  = idx >> 9;
    int b  = m >> 10, l = m & (SEQ - 1);
    const ushort_t* xb = xzall + (size_t)b * SEQ * (4 * DI) + dir * (2 * DI) + di;
    float wv[4][4];
#pragma unroll
    for (int c = 0; c < 4; c++) {
        float4 w = *(const float4*)(convW + (di + c) * 4);
        wv[c][0] = w.x; wv[c][1] = w.y; wv[c][2] = w.z; wv[c][3] = w.w;
    }
    float4 cb = *(const float4*)(convB + di);
    float acc[4] = {cb.x, cb.y, cb.z, cb.w};
#pragma unroll
    for (int j = 0; j < 4; j++) {
        int srcl = dir ? (l + 3 - j) : (l - 3 + j);
        if ((unsigned)srcl < SEQ) {
            ushort4 xv = *(const ushort4*)(xb + (size_t)srcl * (4 * DI));
            acc[0] += wv[0][j] * bf2f(xv.x);
            acc[1] += wv[1][j] * bf2f(xv.y);
            acc[2] += wv[2][j] * bf2f(xv.z);
            acc[3] += wv[3][j] * bf2f(xv.w);
        }
    }
    ushort4 o;
    o.x = f2bf(acc[0] / (1.f + __expf(-acc[0])));
    o.y = f2bf(acc[1] / (1.f + __expf(-acc[1])));
    o.z = f2bf(acc[2] / (1.f + __expf(-acc[2])));
    o.w = f2bf(acc[3] / (1.f + __expf(-acc[3])));
    *(ushort4*)(ubf + (size_t)dir * M_TOT * DI + (size_t)m * DI + di) = o;
}

__device__ __forceinline__ void gemm2_body(int job, int tid,
    const ushort_t* ubf, const ushort_t* xpWcat, float* part2,
    ushort_t* As, ushort_t* Ws)
{
    const int lane = tid & 63;
    const int wave = tid >> 6;
    int nt = job & 1;
    int mt = (job >> 1) & 31;
    int z  = job >> 6;
    int dir = z >> 3;
    int kz  = z & 7;
    const ushort_t* A = ubf + (size_t)dir * M_TOT * DI;
    const ushort_t* W = xpWcat + (size_t)dir * XPD * DI;
    const int K = DI, N = XPD;
    const int wr = (wave >> 1) * 32;
    const int wc = (wave & 1) * 32;
    f32x4 acc[2][2] = {};
    const int m0 = mt * 64;
    const int n0 = nt * 64;
    const int kStart = kz * (DI / 8);
    const int srow = tid >> 3;
    const int scol = (tid & 7) << 3;
    for (int k0 = kStart; k0 < kStart + DI / 8; k0 += 64) {
        {
            int r = srow;
            *(short8*)(&As[r * LDSP + scol]) =
                *(const short8*)(A + (size_t)(m0 + r) * K + k0 + scol);
            int r2 = 32 + srow;
            *(short8*)(&As[r2 * LDSP + scol]) =
                *(const short8*)(A + (size_t)(m0 + r2) * K + k0 + scol);
            int wn = n0 + r;
            short8 wvv = {};
            if (wn < N) wvv = *(const short8*)(W + (size_t)wn * K + k0 + scol);
            *(short8*)(&Ws[r * LDSP + scol]) = wvv;
            int wn2 = n0 + r2;
            short8 wv2 = {};
            if (wn2 < N) wv2 = *(const short8*)(W + (size_t)wn2 * K + k0 + scol);
            *(short8*)(&Ws[r2 * LDSP + scol]) = wv2;
        }
        __syncthreads();
#pragma unroll
        for (int kk = 0; kk < 2; kk++) {
            const int kcol = kk * 32 + ((lane >> 4) << 3);
            short8 af[2], bfr[2];
#pragma unroll
            for (int i = 0; i < 2; i++)
                af[i] = *(const short8*)(&As[(wr + i * 16 + (lane & 15)) * LDSP + kcol]);
#pragma unroll
            for (int j = 0; j < 2; j++)
                bfr[j] = *(const short8*)(&Ws[(wc + j * 16 + (lane & 15)) * LDSP + kcol]);
#pragma unroll
            for (int i = 0; i < 2; i++)
#pragma unroll
                for (int j = 0; j < 2; j++)
                    acc[i][j] = __builtin_amdgcn_mfma_f32_16x16x32_bf16(
                        af[i], bfr[j], acc[i][j], 0, 0, 0);
        }
        __syncthreads();
    }
    float* Pz = part2 + ((size_t)dir * 8 + kz) * M_TOT * XPD;
#pragma unroll
    for (int i = 0; i < 2; i++)
#pragma unroll
        for (int r = 0; r < 4; r++) {
            int m = m0 + wr + i * 16 + ((lane >> 4) << 2) + r;
#pragma unroll
            for (int j = 0; j < 2; j++) {
                int n = n0 + wc + j * 16 + (lane & 15);
                if (n < N) Pz[(size_t)m * XPD + n] = acc[i][j][r];
            }
        }
}

__device__ __forceinline__ void xdblred_body(int job, int tid,
    const float* part2, float* xdbl)
{
    int dir = job >= 192;
    int i = (job - dir * 192) * 256 + tid;
    const size_t S = (size_t)M_TOT * XPD / 4;
    const float4* Pd = (const float4*)(part2 + (size_t)dir * 8 * M_TOT * XPD);
    float4 s = Pd[i];
#pragma unroll
    for (int z = 1; z < 8; z++) {
        float4 v = Pd[i + z * S];
        s.x += v.x; s.y += v.y; s.z += v.z; s.w += v.w;
    }
    ((float4*)(xdbl + (size_t)dir * M_TOT * XPD))[i] = s;
}

__device__ __forceinline__ void delta_body(int job, int tid,
    const float* xdbl, const float* dtWf, const float* dtWb,
    const float* dtBf, const float* dtBb, ushort_t* deltab,
    ushort_t* As, ushort_t* Ws)
{
    const int lane = tid & 63;
    const int wave = tid >> 6;
    int nt = job & 31;
    int mt = (job >> 5) & 31;
    int dir = job >> 10;
    const float* xd  = xdbl + (size_t)dir * M_TOT * XPD;
    const float* dtW = dir ? dtWb : dtWf;
    const float* dtB = dir ? dtBb : dtBf;
    ushort_t* delta  = deltab + (size_t)dir * M_TOT * DI;
    const int wr = (wave >> 1) * 32;
    const int wc = (wave & 1) * 32;
    const int m0 = mt * 64;
    const int n0 = nt * 64;
    const int srow = tid >> 2;
    const int scol = (tid & 3) << 4;
    {
        const float* ap = xd  + (size_t)(m0 + srow) * XPD + scol;
        const float* wp = dtW + (size_t)(n0 + srow) * RNK + scol;
        float4 av[4], wv[4];
#pragma unroll
        for (int q = 0; q < 4; q++) { av[q] = ((const float4*)ap)[q]; wv[q] = ((const float4*)wp)[q]; }
        __align__(16) ushort_t at[16], wt[16];
#pragma unroll
        for (int q = 0; q < 16; q++) {
            at[q] = f2bf(((const float*)av)[q]);
            wt[q] = f2bf(((const float*)wv)[q]);
        }
        *(short8*)(&As[srow * LDSP + scol])     = *(const short8*)(at);
        *(short8*)(&As[srow * LDSP + scol + 8]) = *(const short8*)(at + 8);
        *(short8*)(&Ws[srow * LDSP + scol])     = *(const short8*)(wt);
        *(short8*)(&Ws[srow * LDSP + scol + 8]) = *(const short8*)(wt + 8);
    }
    __syncthreads();
    f32x4 acc[2][2] = {};
#pragma unroll
    for (int kk = 0; kk < 2; kk++) {
        const int kcol = kk * 32 + ((lane >> 4) << 3);
        short8 af[2], bfr[2];
#pragma unroll
        for (int i = 0; i < 2; i++)
            af[i] = *(const short8*)(&As[(wr + i * 16 + (lane & 15)) * LDSP + kcol]);
#pragma unroll
        for (int j = 0; j < 2; j++)
            bfr[j] = *(const short8*)(&Ws[(wc + j * 16 + (lane & 15)) * LDSP + kcol]);
#pragma unroll
        for (int i = 0; i < 2; i++)
#pragma unroll
            for (int j = 0; j < 2; j++)
                acc[i][j] = __builtin_amdgcn_mfma_f32_16x16x32_bf16(
                    af[i], bfr[j], acc[i][j], 0, 0, 0);
    }
#pragma unroll
    for (int j = 0; j < 2; j++) {
        int n = n0 + wc + j * 16 + (lane & 15);
        float bn = dtB[n];
#pragma unroll
        for (int i = 0; i < 2; i++) {
#pragma unroll
            for (int r = 0; r < 4; r++) {
                int m = m0 + wr + i * 16 + ((lane >> 4) << 2) + r;
                float v = acc[i][j][r] + bn;
                float sp = (v > 20.f) ? v : log1pf(__expf(v));
                delta[(size_t)m * DI + n] = f2bf(sp);
            }
        }
    }
    __syncthreads();   // LDS reuse across grid-stride reps
}

__device__ __forceinline__ void scan1_body(int job, int tid,
    const ushort_t* deltab, const ushort_t* ubf, const float* xdbl,
    const float* Alogf, const float* Alogb, float* Sb, float* SD)
{
    const int lane = tid & 63;
    const int wave = tid >> 6;
    int dir = job >> 9;
    int blk = job & 511;
    int dg = blk & 7;
    int bc = blk >> 3;
    int c  = bc & (NC - 1);
    int b  = bc >> 5;
    int d  = (dg * 4 + wave) * 64 + lane;
    int t0 = dir ? (SEQ - 1 - c * LC) : (c * LC);
    int rs = dir ? -1 : 1;
    const float* Alog = dir ? Alogb : Alogf;
    const ushort_t* dl_p = deltab + (size_t)dir * M_TOT * DI;
    const ushort_t* u_p  = ubf    + (size_t)dir * M_TOT * DI;
    const float*    xd   = xdbl   + (size_t)dir * M_TOT * XPD;
    float* Sbd = Sb + (size_t)dir * NC * NCH;
    float* SDd = SD + (size_t)dir * NC * B_SZ * DI;

    float ac2[NST];
#pragma unroll
    for (int q = 0; q < 4; q++) {
        float4 al = *(const float4*)(Alog + (size_t)d * NST + q * 4);
        ac2[q * 4 + 0] = -__expf(al.x) * LOG2E;
        ac2[q * 4 + 1] = -__expf(al.y) * LOG2E;
        ac2[q * 4 + 2] = -__expf(al.z) * LOG2E;
        ac2[q * 4 + 3] = -__expf(al.w) * LOG2E;
    }
    float h[NST];
#pragma unroll
    for (int n = 0; n < NST; n++) h[n] = 0.f;
    float sumD = 0.f;
#pragma unroll 4
    for (int l = 0; l < LC; l++) {
        int t = t0 + rs * l;
        size_t row = (size_t)b * SEQ + t;
        float dl = bf2f(dl_p[row * DI + d]);
        float uv = bf2f(u_p[row * DI + d]);
        const float* xr = xd + row * XPD + RNK;
        float4 Bv[4];
#pragma unroll
        for (int q = 0; q < 4; q++) Bv[q] = *(const float4*)(xr + q * 4);
        float dlu = dl * uv;
        sumD += dl;
#pragma unroll
        for (int n = 0; n < NST; n++) {
            float dA = EXP2F(dl * ac2[n]);
            h[n] = h[n] * dA + dlu * ((const float*)Bv)[n];
        }
    }
    size_t o = (size_t)c * NCH + ((size_t)b * DI + d) * NST;
#pragma unroll
    for (int q = 0; q < 4; q++)
        *(float4*)(Sbd + o + q * 4) = make_float4(h[q*4], h[q*4+1], h[q*4+2], h[q*4+3]);
    SDd[(size_t)c * (B_SZ * DI) + b * DI + d] = sumD;
}

__device__ __forceinline__ void combine_body(int job, int tid,
    float* Sb, const float* SD, const float* Alogf, const float* Alogb)
{
    int gid = job * 256 + tid;
    int dir = gid >= NCH;
    int i = gid - dir * NCH;
    int n = i & 15;
    int d = (i >> 4) & (DI - 1);
    int b = i >> 15;
    const float* Alog = dir ? Alogb : Alogf;
    float* Sbd = Sb + (size_t)dir * NC * NCH;
    const float* SDd = SD + (size_t)dir * NC * B_SZ * DI;
    float ac2 = -__expf(Alog[(size_t)d * NST + n]) * LOG2E;
    float h = 0.f;
#pragma unroll
    for (int c = 0; c < NC; c++) {
        float s = Sbd[(size_t)c * NCH + i];
        float p = EXP2F(ac2 * SDd[(size_t)c * (B_SZ * DI) + b * DI + d]);
        Sbd[(size_t)c * NCH + i] = h;
        h = s + p * h;
    }
}

__device__ __forceinline__ void scan2_body(int job, int tid,
    const ushort_t* deltab, const ushort_t* ubf, const float* xdbl,
    const ushort_t* xzall, const float* Alogf, const float* Alogb,
    const float* Dpf, const float* Dpb, const float* Hinit, ushort_t* ybf)
{
    const int lane = tid & 63;
    const int wave = tid >> 6;
    int dir = job >> 9;
    int blk = job & 511;
    int dg = blk & 7;
    int bc = blk >> 3;
    int c  = bc & (NC - 1);
    int b  = bc >> 5;
    int d  = (dg * 4 + wave) * 64 + lane;
    int t0 = dir ? (SEQ - 1 - c * LC) : (c * LC);
    int rs = dir ? -1 : 1;
    const float* Alog = dir ? Alogb : Alogf;
    const float* Dpp  = dir ? Dpb : Dpf;
    const ushort_t* dl_p = deltab + (size_t)dir * M_TOT * DI;
    const ushort_t* u_p  = ubf    + (size_t)dir * M_TOT * DI;
    const float*    xd   = xdbl   + (size_t)dir * M_TOT * XPD;
    const float*    Hin  = Hinit  + (size_t)dir * NC * NCH;

    float ac2[NST];
#pragma unroll
    for (int q = 0; q < 4; q++) {
        float4 al = *(const float4*)(Alog + (size_t)d * NST + q * 4);
        ac2[q * 4 + 0] = -__expf(al.x) * LOG2E;
        ac2[q * 4 + 1] = -__expf(al.y) * LOG2E;
        ac2[q * 4 + 2] = -__expf(al.z) * LOG2E;
        ac2[q * 4 + 3] = -__expf(al.w) * LOG2E;
    }
    float dp = Dpp[d];
    float h[NST];
    {
        size_t o = (size_t)c * NCH + ((size_t)b * DI + d) * NST;
#pragma unroll
        for (int q = 0; q < 4; q++) {
            float4 hv = *(const float4*)(Hin + o + q * 4);
            h[q*4] = hv.x; h[q*4+1] = hv.y; h[q*4+2] = hv.z; h[q*4+3] = hv.w;
        }
    }
#pragma unroll 4
    for (int l = 0; l < LC; l++) {
        int t = t0 + rs * l;
        size_t row = (size_t)b * SEQ + t;
        float dl = bf2f(dl_p[row * DI + d]);
        float uv = bf2f(u_p[row * DI + d]);
        const float* xr = xd + row * XPD + RNK;
        float4 Bv[4], Cv[4];
#pragma unroll
        for (int q = 0; q < 4; q++) {
            Bv[q] = *(const float4*)(xr + q * 4);
            Cv[q] = *(const float4*)(xr + NST + q * 4);
        }
        float dlu = dl * uv;
        float y = 0.f;
#pragma unroll
        for (int n = 0; n < NST; n++) {
            float dA = EXP2F(dl * ac2[n]);
            h[n] = h[n] * dA + dlu * ((const float*)Bv)[n];
            y += h[n] * ((const float*)Cv)[n];
        }
        float z = bf2f(xzall[row * (4 * DI) + dir * (2 * DI) + DI + d]);
        float yv = (y + uv * dp) * (z / (1.f + __expf(-z)));
        ybf[row * (2 * DI) + dir * DI + d] = f2bf(yv);
    }
}

// ===========================================================================
// Fallback standalone kernels (R9-equivalent launches)
// ===========================================================================
__global__ __launch_bounds__(256)
void conv_silu2(const ushort_t* __restrict__ xzall,
                const float* __restrict__ convWf, const float* __restrict__ convWb,
                const float* __restrict__ convBf, const float* __restrict__ convBb,
                ushort_t* __restrict__ ubf)
{
    conv_body(blockIdx.x, threadIdx.x, xzall, convWf, convWb, convBf, convBb, ubf);
}

__global__ __launch_bounds__(256)
void gemm2_splitk2(const ushort_t* __restrict__ ubf, const ushort_t* __restrict__ xpWcat,
                   float* __restrict__ P)
{
    __shared__ __align__(16) ushort_t As[64 * LDSP];
    __shared__ __align__(16) ushort_t Ws[64 * LDSP];
    gemm2_body(blockIdx.x, threadIdx.x, ubf, xpWcat, P, As, Ws);
}

__global__ __launch_bounds__(256)
void xdbl_reduce2(const float* __restrict__ P, float* __restrict__ xdbl)
{
    xdblred_body(blockIdx.x, threadIdx.x, P, xdbl);
}

__global__ __launch_bounds__(256)
void delta_gemm2(const float* __restrict__ xdbl,
                 const float* __restrict__ dtWf, const float* __restrict__ dtWb,
                 const float* __restrict__ dtBf, const float* __restrict__ dtBb,
                 ushort_t* __restrict__ deltab)
{
    __shared__ __align__(16) ushort_t As[64 * LDSP];
    __shared__ __align__(16) ushort_t Ws[64 * LDSP];
    delta_body(blockIdx.x, threadIdx.x, xdbl, dtWf, dtWb, dtBf, dtBb, deltab, As, Ws);
}

__global__ __launch_bounds__(256)
void scan_pass1_2(const ushort_t* __restrict__ deltab, const ushort_t* __restrict__ ubf,
                  const float* __restrict__ xdbl,
                  const float* __restrict__ Alogf, const float* __restrict__ Alogb,
                  float* __restrict__ Sb, float* __restrict__ SD)
{
    scan1_body(blockIdx.x, threadIdx.x, deltab, ubf, xdbl, Alogf, Alogb, Sb, SD);
}

__global__ __launch_bounds__(256)
void scan_combine2(float* __restrict__ Sb, const float* __restrict__ SD,
                   const float* __restrict__ Alogf, const float* __restrict__ Alogb)
{
    combine_body(blockIdx.x, threadIdx.x, Sb, SD, Alogf, Alogb);
}

__global__ __launch_bounds__(256)
void scan_pass2_2(const ushort_t* __restrict__ deltab, const ushort_t* __restrict__ ubf,
                  const float* __restrict__ xdbl, const ushort_t* __restrict__ xzall,
                  const float* __restrict__ Alogf, const float* __restrict__ Alogb,
                  const float* __restrict__ Dpf, const float* __restrict__ Dpb,
                  const float* __restrict__ Hinit, ushort_t* __restrict__ ybf)
{
    scan2_body(blockIdx.x, threadIdx.x, deltab, ubf, xdbl, xzall, Alogf, Alogb,
               Dpf, Dpb, Hinit, ybf);
}

// ===========================================================================
// Cooperative mega-kernels: 512 blocks (2/CU), uniform grid-stride phases.
// ===========================================================================
struct MidArgs {
    const ushort_t* xzall;
    ushort_t* ubf;
    const ushort_t* xpWcat;
    float* part2;
    float* xdbl;
    ushort_t* deltab;
    float* Sb;
    float* SD;
    ushort_t* ybf;
    const float* convWf; const float* convWb;
    const float* convBf; const float* convBb;
    const float* dtWf;   const float* dtWb;
    const float* dtBf;   const float* dtBb;
    const float* Alogf;  const float* Alogb;
    const float* Dpf;    const float* Dpb;
};

__global__ __launch_bounds__(256, 2)
void coop_mid(MidArgs a)
{
    cg::grid_group grid = cg::this_grid();
    __shared__ __align__(16) ushort_t As[64 * LDSP];
    __shared__ __align__(16) ushort_t Ws[64 * LDSP];
    const int tid = threadIdx.x;
    const int bid = blockIdx.x;

    for (int job = bid; job < 8192; job += CGB)    // phase 1: conv (16/blk)
        conv_body(job, tid, a.xzall, a.convWf, a.convWb, a.convBf, a.convBb, a.ubf);
    __threadfence(); grid.sync();

    for (int job = bid; job < 1024; job += CGB)    // phase 2: gemm2 (2/blk, uniform)
        gemm2_body(job, tid, a.ubf, a.xpWcat, a.part2, As, Ws);
    __threadfence(); grid.sync();

    for (int job = bid; job < 384; job += CGB)     // phase 3: xdbl reduce
        xdblred_body(job, tid, a.part2, a.xdbl);
    __threadfence(); grid.sync();

    for (int job = bid; job < 2048; job += CGB)    // phase 4: delta (4/blk, uniform)
        delta_body(job, tid, a.xdbl, a.dtWf, a.dtWb, a.dtBf, a.dtBb, a.deltab, As, Ws);
    __threadfence(); grid.sync();

    for (int job = bid; job < 1024; job += CGB)    // phase 5: scan1 (2/blk)
        scan1_body(job, tid, a.deltab, a.ubf, a.xdbl, a.Alogf, a.Alogb, a.Sb, a.SD);
    __threadfence(); grid.sync();

    for (int job = bid; job < 512; job += CGB)     // phase 6: combine (1/blk)
        combine_body(job, tid, a.Sb, a.SD, a.Alogf, a.Alogb);
    __threadfence(); grid.sync();

    for (int job = bid; job < 1024; job += CGB)    // phase 7: scan2 (2/blk)
        scan2_body(job, tid, a.deltab, a.ubf, a.xdbl, a.xzall, a.Alogf, a.Alogb,
                   a.Dpf, a.Dpb, a.Sb, a.ybf);
}

struct OutArgs {
    const ushort_t* ybf;
    const ushort_t* outWcat;
    float* part;
    float* out;
};

__global__ __launch_bounds__(256, 2)
void coop_out(OutArgs a)
{
    cg::grid_group grid = cg::this_grid();
    __shared__ __align__(16) ushort_t As[128 * 64];
    __shared__ __align__(16) ushort_t Ws[128 * 64];
    const int tid  = threadIdx.x;
    const int bid  = blockIdx.x;
    const int lane = tid & 63;
    const int wave = tid >> 6;

    // phase 1: GEMM4 splitK=4 partials (512 jobs, 1/blk)
    {
        const int nt = bid & 7;
        const int mt = (bid >> 3) & 15;
        const int z  = bid >> 7;
        const int K = 2 * DI, kLen = DI / 2, ldD = DM;
        const int wr = (wave >> 1) * 64;
        const int wc = (wave & 1) * 64;
        const int m0 = mt * 128;
        const int n0 = nt * 128;
        const int kStart = z * kLen;
        const int srow   = lane >> 3;
        const int gchunk = (lane & 7) ^ srow;
        f32x4 acc[4][4] = {};
        for (int k0 = kStart; k0 < kStart + kLen; k0 += 64) {
#pragma unroll
            for (int it = 0; it < 4; it++) {
                const int rb = wave * 32 + it * 8;
                load_lds16(a.ybf + (size_t)(m0 + rb + srow) * K + k0 + gchunk * 8, As + rb * 64);
                load_lds16(a.outWcat + (size_t)(n0 + rb + srow) * K + k0 + gchunk * 8, Ws + rb * 64);
            }
            __syncthreads();
#pragma unroll
            for (int kk = 0; kk < 2; kk++) {
                const int kc = kk * 4 + (lane >> 4);
                short8 af[4], bf[4];
#pragma unroll
                for (int i = 0; i < 4; i++) {
                    int r = wr + i * 16 + (lane & 15);
                    af[i] = *(const short8*)(As + r * 64 + ((kc ^ (r & 7)) << 3));
                }
#pragma unroll
                for (int j = 0; j < 4; j++) {
                    int r = wc + j * 16 + (lane & 15);
                    bf[j] = *(const short8*)(Ws + r * 64 + ((kc ^ (r & 7)) << 3));
                }
#pragma unroll
                for (int i = 0; i < 4; i++)
#pragma unroll
                    for (int j = 0; j < 4; j++)
                        acc[i][j] = __builtin_amdgcn_mfma_f32_16x16x32_bf16(
                            af[i], bf[j], acc[i][j], 0, 0, 0);
            }
            __syncthreads();
        }
        float* Dp = a.part + (size_t)z * M_TOT * ldD;
#pragma unroll
        for (int i = 0; i < 4; i++)
#pragma unroll
            for (int r = 0; r < 4; r++) {
                int m = m0 + wr + i * 16 + ((lane >> 4) << 2) + r;
#pragma unroll
                for (int j = 0; j < 4; j++) {
                    int n = n0 + wc + j * 16 + (lane & 15);
                    Dp[(size_t)m * ldD + n] = acc[i][j][r];
                }
            }
    }
    __threadfence();
    grid.sync();

    // phase 2: out = 0.5 * sum of 4 partials (2048 jobs, 4/blk)
    const size_t S = (size_t)M_TOT * DM / 4;
#pragma unroll
    for (int rep = 0; rep < 4; rep++) {
        int i = (bid * 4 + rep) * 256 + tid;
        float4 p0 = ((const float4*)a.part)[i];
        float4 p1 = ((const float4*)a.part)[i + S];
        float4 p2 = ((const float4*)a.part)[i + 2 * S];
        float4 p3 = ((const float4*)a.part)[i + 3 * S];
        float4 o;
        o.x = 0.5f * (p0.x + p1.x + p2.x + p3.x);
        o.y = 0.5f * (p0.y + p1.y + p2.y + p3.y);
        o.z = 0.5f * (p0.z + p1.z + p2.z + p3.z);
        o.w = 0.5f * (p0.w + p1.w + p2.w + p3.w);
        ((float4*)a.out)[i] = o;
    }
}

// ---------------------------------------------------------------------------
extern "C" void kernel_launch(void* const* d_in, const int* in_sizes, int n_in,
                              void* d_out, int out_size, void* d_ws, size_t ws_size,
                              hipStream_t stream)
{
    char* wsb = (char*)d_ws;

    ushort_t* xzall  = (ushort_t*)wsb;                 // 33,554,432 [M x 8192] bf16
    ushort_t* ybf    = (ushort_t*)(wsb + 33554432);    // 16,777,216 [M x 2*DI] bf16
    ushort_t* inWcat = (ushort_t*)(wsb + 50331648);    // 16,777,216
    ushort_t* outWcat= (ushort_t*)(wsb + 67108864);    //  8,388,608 [DM x 2*DI] bf16
    ushort_t* xbf    = (ushort_t*)(wsb + 75497472);    //  4,194,304 [M x DM] bf16
    ushort_t* xpWcat = (ushort_t*)(wsb + 79691776);    //    786,432 [2][XPD x DI] bf16
    ushort_t* ubf    = (ushort_t*)(wsb + 80478208);    // 16,777,216 [2][M x DI] bf16
    ushort_t* deltab = (ushort_t*)(wsb + 97255424);    // 16,777,216 [2][M x DI] bf16
    float*    xdbl   = (float*)(wsb + 114032640);      //  1,572,864 [2][M x XPD] fp32

    // overlays (dead regions):
    float* Sb    = (float*)inWcat;                     // after GEMM1
    float* SD    = (float*)xbf;                        // after GEMM1
    float* part2 = (float*)deltab;                     // pre-delta
    float* part4 = (float*)xzall;                      // after scans

    float* out = (float*)d_out;
    dim3 blk(256);

    // 1. prologue conversions
    convert_all<<<14720, blk, 0, stream>>>(
        (const float*)d_in[0], (const float*)d_in[1], (const float*)d_in[10],
        (const float*)d_in[9], (const float*)d_in[18],
        (const float*)d_in[4], (const float*)d_in[13],
        xbf, inWcat, outWcat, xpWcat);

    // 2. xzall = x * [inW_f; inW_b]^T
    gemm_gll<true><<<dim3(8192 / 128, M_TOT / 128, 1), blk, 0, stream>>>(
        xbf, inWcat, xzall, M_TOT, 8192, DM, DM, 8192);

    // 3. cooperative middle (512 blocks); fallback to R9 sequence on failure
    MidArgs margs;
    margs.xzall = xzall; margs.ubf = ubf; margs.xpWcat = xpWcat;
    margs.part2 = part2; margs.xdbl = xdbl; margs.deltab = deltab;
    margs.Sb = Sb; margs.SD = SD; margs.ybf = ybf;
    margs.convWf = (const float*)d_in[2];  margs.convWb = (const float*)d_in[11];
    margs.convBf = (const float*)d_in[3];  margs.convBb = (const float*)d_in[12];
    margs.dtWf   = (const float*)d_in[5];  margs.dtWb   = (const float*)d_in[14];
    margs.dtBf   = (const float*)d_in[6];  margs.dtBb   = (const float*)d_in[15];
    margs.Alogf  = (const float*)d_in[7];  margs.Alogb  = (const float*)d_in[16];
    margs.Dpf    = (const float*)d_in[8];  margs.Dpb    = (const float*)d_in[17];
    void* kargs1[] = { &margs };
    hipError_t e1 = hipLaunchCooperativeKernel((void*)coop_mid, dim3(CGB), blk,
                                               kargs1, 0, stream);
    if (e1 != hipSuccess) {
        (void)hipGetLastError();
        conv_silu2<<<8192, blk, 0, stream>>>(xzall, margs.convWf, margs.convWb,
                                             margs.convBf, margs.convBb, ubf);
        gemm2_splitk2<<<1024, blk, 0, stream>>>(ubf, xpWcat, part2);
        xdbl_reduce2<<<384, blk, 0, stream>>>(part2, xdbl);
        delta_gemm2<<<2048, blk, 0, stream>>>(xdbl, margs.dtWf, margs.dtWb,
                                              margs.dtBf, margs.dtBb, deltab);
        scan_pass1_2<<<1024, blk, 0, stream>>>(deltab, ubf, xdbl,
                                               margs.Alogf, margs.Alogb, Sb, SD);
        scan_combine2<<<512, blk, 0, stream>>>(Sb, SD, margs.Alogf, margs.Alogb);
        scan_pass2_2<<<1024, blk, 0, stream>>>(deltab, ubf, xdbl, xzall,
                                               margs.Alogf, margs.Alogb,
                                               margs.Dpf, margs.Dpb, Sb, ybf);
    }

    // 4. cooperative output; fallback on failure
    OutArgs oargs;
    oargs.ybf = ybf; oargs.outWcat = outWcat; oargs.part = part4; oargs.out = out;
    void* kargs2[] = { &oargs };
    hipError_t e2 = hipLaunchCooperativeKernel((void*)coop_out, dim3(CGB), blk,
                                               kargs2, 0, stream);
    if (e2 != hipSuccess) {
        (void)hipGetLastError();
        gemm_gll<false><<<dim3(DM / 128, M_TOT / 128, 4), blk, 0, stream>>>(
            ybf, outWcat, part4, M_TOT, DM, 2 * DI, DI / 2, DM);
        reduce4<<<(M_TOT * DM / 4) / 256, blk, 0, stream>>>(part4, out);
    }
}